// Round 5
// baseline (297.140 us; speedup 1.0000x reference)
//
#include <hip/hip_runtime.h>

// Problem constants (fixed by the reference's setup_inputs).
#define BATCH 8
#define CH    16
#define HH    512
#define WW    512
#define HW    (HH * WW)     // 262144

#define TILE  32            // output tile edge per block
#define RPAD  16            // halo radius staged in LDS
#define REGE  64            // staged region edge = TILE + 2*RPAD
#define NPX   4             // pixels per thread = TILE*TILE / 256

// R5: pure counted-vmcnt queue (in-phase stores) + ds_read2 gather.
//
// R4 post-mortem: VGPR_Count=68 proved res[16][4] (64 floats) went to
// SCRATCH -- scratch VMEM ops entered the vmcnt queue and polluted the
// counted waits (the pipeline R4 built). R5 removes the register
// accumulator entirely: each phase stores its 4 outputs BEFORE the counted
// wait, so stores are explicit, counted, in-order queue members:
//   phase g: GATHERST(g, g%3); s_waitcnt vmcnt(N); s_barrier;
//            STAGE(g+3, g%3)
// steady-state queue at the wait (oldest->newest) =
//   [st(g-1)x4, S(g+1)x4-being-retired, ... ] -> N=12 retires exactly
// S(g+1) (phase 0: N=8; tail: 12, 8, none -- derived per phase below).
// Stores are never waited on (they retire naturally, >=2 phases old when
// they'd matter). Never vmcnt(0) in the loop.
//
// Second change: FORCED unit-stride corners. Validity is folded into the
// weights, so any corner whose true coordinate is out of image has weight
// exactly 0 -- its fetched value is irrelevant. Therefore the gather reads
// l, l+1, l+64, l+65 unconditionally (exact whenever dx==1 && dy==1).
// Pixels where border clamping collapsed a coordinate (dx==0 || dy==0,
// i.e. sampling within 1px of the image border; only reachable in border
// tiles, ~2% of pixels) are flagged into fbmask and recomputed exactly by
// the global-gather fixup (same thread stores both -> program order gives
// the final value). Constant offsets {0,1},{64,65} from one base fuse into
// ds_read2_b32: 256 -> 128 LDS instrs/thread, and dxv/dyov disappear.
//
// Staging: __builtin_amdgcn_global_load_lds width=16; one instr per wave =
// 1 KB = 4 rows of the 64x64 fp32 plane (wave-uniform LDS base + lane*16;
// per-lane global source). buf[3][64][64] = 48 KB -> 3 blocks/CU. Source
// chunks are 16B-aligned (x0r multiple of 16 floats) and never straddle an
// image row; fully-out-of-image chunks are offset-clamped -> finite garbage
// only in cells that no weight-nonzero corner of a non-fixup pixel can
// reference.
//
// Kept: XCD-contiguous blockIdx swizzle (bijective, 2048%8==0), flow loads
// hoisted oldest in the vmcnt queue, fbmask + fixup-recompute, mask folded
// into weights on UNCLIPPED floor coords (bit-exact vs reference).

typedef __attribute__((address_space(1))) const void global_cvoid;
typedef __attribute__((address_space(3))) void lds_void;

__device__ __forceinline__ void gll16(const float* g, float* l) {
    __builtin_amdgcn_global_load_lds((global_cvoid*)g, (lds_void*)l, 16, 0, 0);
}

#define WAITVM(n) asm volatile("s_waitcnt vmcnt(" #n ")" ::: "memory")
#define BAR()     do { __builtin_amdgcn_s_barrier();                    \
                       __builtin_amdgcn_sched_barrier(0); } while (0)

// Stage channel plane g into buffer nb: 4 gll16 per wave (quads k*4+wv).
#define STAGE(g, nb) do {                                               \
    const float* pc_ = img + ib + (size_t)(g) * HW;                     \
    _Pragma("unroll")                                                   \
    for (int k_ = 0; k_ < 4; ++k_) {                                    \
        gll16(pc_ + goff[k_], &buf[nb][(k_ * 4 + wv) * 4][0]);          \
    }                                                                   \
} while (0)

// Gather channel g from buffer cb and store directly (counted stores).
// Forced unit-stride corners: l, l+1, l+64, l+65 (see header comment).
#define GATHERST(g, cb) do {                                            \
    const float* pl_ = &buf[cb][0][0];                                  \
    float* o0_ = out + ib + (size_t)(g) * HW;                           \
    _Pragma("unroll")                                                   \
    for (int p_ = 0; p_ < NPX; ++p_) {                                  \
        const int l_ = lidx[p_];                                        \
        const float v00 = pl_[l_];                                      \
        const float v01 = pl_[l_ + 1];                                  \
        const float v10 = pl_[l_ + REGE];                               \
        const float v11 = pl_[l_ + REGE + 1];                           \
        o0_[obase[p_]] = w00[p_]*v00 + w01[p_]*v01                      \
                       + w10[p_]*v10 + w11[p_]*v11;                     \
    }                                                                   \
} while (0)

__global__ __launch_bounds__(256, 3) void warp_ds2(
    const float* __restrict__ img,
    const float* __restrict__ flo,
    float* __restrict__ out)
{
    __shared__ float buf[3][REGE][REGE];   // 48 KB -> 3 blocks/CU

    const int t   = threadIdx.x;
    const int bid = blockIdx.x;           // 0..2047
    const int tile = (bid & 7) * 256 + (bid >> 3);   // XCD-contiguous chunks
    const int b    = tile >> 8;
    const int ty   = (tile >> 4) & 15;
    const int tx   = tile & 15;
    const int xb   = tx * TILE;
    const int yb   = ty * TILE;
    const int x0r  = xb - RPAD;           // region origin (may be negative)
    const int y0r  = yb - RPAD;

    // ---- staging geometry (channel-invariant) ----
    const int lane = t & 63;
    const int wv   = t >> 6;              // wave id 0..3 (wave-uniform)
    const int sub  = lane >> 4;           // row-within-quad 0..3
    const int xch  = x0r + (lane & 15) * 4;  // this lane's 4-float x chunk
    const size_t ib = (size_t)b * CH * HW;

    int goff[4];                          // per-lane staged global offsets
#pragma unroll
    for (int k = 0; k < 4; ++k) {
        const int q  = k * 4 + wv;        // quad 0..15
        const int ry = q * 4 + sub;       // this lane's region row 0..63
        const int gy = min(max(y0r + ry, 0), HH - 1);
        goff[k] = min(max(gy * WW + xch, 0), HW - 4);
    }

    // ---- flow loads FIRST (oldest in the in-order vmcnt queue) ----
    const float* fbp = flo + (size_t)b * 2 * HW;
    float fxv[NPX], fyv[NPX];
#pragma unroll
    for (int p = 0; p < NPX; ++p) {
        const int pix = p * 256 + t;
        const int hw  = (yb + (pix >> 5)) * WW + xb + (pix & 31);
        fxv[p] = fbp[hw];                 // coalesced
        fyv[p] = fbp[HW + hw];
    }
    asm volatile("" ::: "memory");        // pin: flow loads precede all gll

    // ---- pre-issue staging for groups 0..2 (all three buffers) ----
    STAGE(0, 0);
    STAGE(1, 1);
    STAGE(2, 2);

    // ---- per-pixel precompute (register-only; hides staging latency) ----
    float w00[NPX], w01[NPX], w10[NPX], w11[NPX];
    int   lidx[NPX], obase[NPX];
    int   fbmask = 0;

#pragma unroll
    for (int p = 0; p < NPX; ++p) {
        const int pix = p * 256 + t;      // 0..1023 within tile
        const int row = pix >> 5;
        const int col = pix & 31;
        const int h   = yb + row;
        const int w   = xb + col;
        obase[p] = h * WW + w;

        const float gx = (float)w + fxv[p];
        const float gy = (float)h + fyv[p];

        const float x0f = floorf(gx), y0f = floorf(gy);
        const float wx1 = gx - x0f, wx0 = 1.0f - wx1;
        const float wy1 = gy - y0f, wy0 = 1.0f - wy1;

        const bool vx0 = (x0f >= 0.0f)        && (x0f <= (float)(WW - 1));
        const bool vx1 = (x0f + 1.0f >= 0.0f) && (x0f + 1.0f <= (float)(WW - 1));
        const bool vy0 = (y0f >= 0.0f)        && (y0f <= (float)(HH - 1));
        const bool vy1 = (y0f + 1.0f >= 0.0f) && (y0f + 1.0f <= (float)(HH - 1));

        float a00 = wx0 * wy0 * ((vx0 && vy0) ? 1.0f : 0.0f);
        float a01 = wx1 * wy0 * ((vx1 && vy0) ? 1.0f : 0.0f);
        float a10 = wx0 * wy1 * ((vx0 && vy1) ? 1.0f : 0.0f);
        float a11 = wx1 * wy1 * ((vx1 && vy1) ? 1.0f : 0.0f);

        const float msum = a00 + a01 + a10 + a11;
        const float mask = (msum < 0.9999f) ? 0.0f : 1.0f;
        w00[p] = a00 * mask; w01[p] = a01 * mask;
        w10[p] = a10 * mask; w11[p] = a11 * mask;

        const int x0 = min(max((int)x0f, 0), WW - 1);
        const int x1 = min(max((int)x0f + 1, 0), WW - 1);
        const int y0 = min(max((int)y0f, 0), HH - 1);
        const int y1 = min(max((int)y0f + 1, 0), HH - 1);

        const int dx = x1 - x0;           // 0 or 1; 0 only at image border
        const int dy = y1 - y0;
        const int xl = x0 - x0r;          // region-local (may be out of range)
        const int yl = y0 - y0r;

        // Fixup if: any corner outside the staged region, OR border
        // clamping collapsed a coordinate (dx/dy==0) -- the forced
        // unit-stride gather is only exact for dx==dy==1.
        if (dx == 0 || dy == 0 ||
            !((xl >= 0) && (xl <= REGE - 2) && (yl >= 0) && (yl <= REGE - 2)))
            fbmask |= (1 << p);
        // Clamp to [0, REGE-2]: no-op for every non-fixup pixel (proven by
        // the condition above), safe-finite for fixup pixels (overwritten).
        lidx[p] = min(max(yl, 0), REGE - 2) * REGE + min(max(xl, 0), REGE - 2);
    }

    // ---- prologue handoff: retire S0 only (S1,S2 stay in flight) ----
    WAITVM(8);
    BAR();

    // ---- 16 phases, counted vmcnt, never a full drain ----
    // Queue accounting (oldest->newest), 4 ops per st/S packet:
    //  P0 : [S1,S2,st0]           =12 -> wait(8)  retires S1
    //  P1 : [S2,st0,S3,st1]       =16 -> wait(12) retires S2
    //  Pk : [st(k-2),S(k+1),st(k-1),S(k+2),st(k)] -> wait(12) retires
    //       st(k-2)+S(k+1), leaving [st(k-1),S(k+2),st(k)]  (k=2..13)
    //  P14: [st12,S15,st13,st14]  =16 -> wait(8)  retires st12+S15
    //  P15: nothing in flight needed
    GATHERST(0, 0);   WAITVM(8);   BAR();  STAGE(3, 0);
    GATHERST(1, 1);   WAITVM(12);  BAR();  STAGE(4, 1);
    GATHERST(2, 2);   WAITVM(12);  BAR();  STAGE(5, 2);
    GATHERST(3, 0);   WAITVM(12);  BAR();  STAGE(6, 0);
    GATHERST(4, 1);   WAITVM(12);  BAR();  STAGE(7, 1);
    GATHERST(5, 2);   WAITVM(12);  BAR();  STAGE(8, 2);
    GATHERST(6, 0);   WAITVM(12);  BAR();  STAGE(9, 0);
    GATHERST(7, 1);   WAITVM(12);  BAR();  STAGE(10, 1);
    GATHERST(8, 2);   WAITVM(12);  BAR();  STAGE(11, 2);
    GATHERST(9, 0);   WAITVM(12);  BAR();  STAGE(12, 0);
    GATHERST(10, 1);  WAITVM(12);  BAR();  STAGE(13, 1);
    GATHERST(11, 2);  WAITVM(12);  BAR();  STAGE(14, 2);
    GATHERST(12, 0);  WAITVM(12);  BAR();  STAGE(15, 0);
    GATHERST(13, 1);  WAITVM(12);  BAR();
    GATHERST(14, 2);  WAITVM(8);   BAR();
    GATHERST(15, 0);

    // ---- fixup: redo fallback pixels from global (all 16 channels) ----
    // Border-clamped + out-of-region pixels (~2-3%). Exact reference math
    // with clamped indices; L2/L3-warm loads.
    if (fbmask) {
#pragma unroll
        for (int p = 0; p < NPX; ++p) {
            if (!(fbmask & (1 << p))) continue;
            const int pix = p * 256 + t;
            const int row = pix >> 5;
            const int col = pix & 31;
            const int h   = yb + row;
            const int w   = xb + col;
            const int hw  = h * WW + w;

            const float gx = (float)w + fxv[p];
            const float gy = (float)h + fyv[p];

            const float x0f = floorf(gx), y0f = floorf(gy);
            const float wx1 = gx - x0f, wx0 = 1.0f - wx1;
            const float wy1 = gy - y0f, wy0 = 1.0f - wy1;

            const bool vx0 = (x0f >= 0.0f)        && (x0f <= (float)(WW - 1));
            const bool vx1 = (x0f + 1.0f >= 0.0f) && (x0f + 1.0f <= (float)(WW - 1));
            const bool vy0 = (y0f >= 0.0f)        && (y0f <= (float)(HH - 1));
            const bool vy1 = (y0f + 1.0f >= 0.0f) && (y0f + 1.0f <= (float)(HH - 1));

            float a00 = wx0 * wy0 * ((vx0 && vy0) ? 1.0f : 0.0f);
            float a01 = wx1 * wy0 * ((vx1 && vy0) ? 1.0f : 0.0f);
            float a10 = wx0 * wy1 * ((vx0 && vy1) ? 1.0f : 0.0f);
            float a11 = wx1 * wy1 * ((vx1 && vy1) ? 1.0f : 0.0f);

            const float msum = a00 + a01 + a10 + a11;
            const float mask = (msum < 0.9999f) ? 0.0f : 1.0f;
            a00 *= mask; a01 *= mask; a10 *= mask; a11 *= mask;

            const int x0 = min(max((int)x0f, 0), WW - 1);
            const int x1 = min(max((int)x0f + 1, 0), WW - 1);
            const int y0 = min(max((int)y0f, 0), HH - 1);
            const int y1 = min(max((int)y0f + 1, 0), HH - 1);

            const int gA  = y0 * WW + x0;
            const int dx  = x1 - x0;
            const int dyo = (y1 - y0) * WW;

            const float* ic = img + ib;
            float*       oc = out + ib + hw;
            for (int c = 0; c < CH; ++c) {
                const float* pc = ic + (size_t)c * HW;
                const float v = a00 * pc[gA]
                              + a01 * pc[gA + dx]
                              + a10 * pc[gA + dyo]
                              + a11 * pc[gA + dx + dyo];
                oc[(size_t)c * HW] = v;
            }
        }
    }
}

extern "C" void kernel_launch(void* const* d_in, const int* in_sizes, int n_in,
                              void* d_out, int out_size, void* d_ws, size_t ws_size,
                              hipStream_t stream) {
    const float* img = (const float*)d_in[0];  // [8,16,512,512] fp32
    const float* flo = (const float*)d_in[1];  // [8,2,512,512] fp32
    float* out = (float*)d_out;                // [8,16,512,512] fp32

    const int blocks = BATCH * (HH / TILE) * (WW / TILE);  // 2048
    warp_ds2<<<blocks, 256, 0, stream>>>(img, flo, out);
}

// Round 6
// 269.902 us; speedup vs baseline: 1.1009x; 1.1009x over previous
//
#include <hip/hip_runtime.h>

// Problem constants (fixed by the reference's setup_inputs).
#define BATCH 8
#define CH    16
#define HH    512
#define WW    512
#define HW    (HH * WW)     // 262144

#define TILW  32            // output tile width per block
#define TILH  64            // output tile height per block
#define RPAD  16            // halo radius staged in LDS
#define REGW  64            // staged region width  = TILW + 2*RPAD
#define REGH  96            // staged region height = TILH + 2*RPAD
#define NPX   4             // pixels per thread = 32*64 / 512
#define NTHR  512

// R6: bigger block (32x64 tile, 8 waves), 16 waves/CU, 3x amplification.
//
// R5 post-mortem: R4's res[16][4] never went to scratch (no scratch traffic
// in FETCH/WRITE) -- the compiler had SUNK the bulk store into the phases
// itself, freely scheduled. R5's manual in-phase stores + sched_barrier(0)
// pinned that schedule (slower), and forced-corner gather tripled the fixup
// set (FETCH +11MB, WRITE +8MB). Both reverted: this is R4's exact schedule
// and gather, scaled.
//
// Scaling theory: R4 was latency-bound (no pipe >27%) -- counted waits had
// only ~2 small phases of cover for staging packets that are ~25% HBM-miss
// (~900cy), with 12 waves/CU. This config: tile 32x64 per 512-thread block,
// region 64x96 fp32, buf[3][96][64] = 72KB -> 2 blocks/CU = 16 waves/CU
// (4/SIMD, was 3) and each phase is 2x bigger -> ~2x the latency cover per
// counted wait. Halo amplification (region/tile) drops 4x -> 3x (issued
// staging 512 -> 384 MB). Grid = 1024 blocks = exactly 2 rounds of the 512
// resident blocks. XCD swizzle (bijective, 1024%8==0) now gives each XCD
// exactly one batch -> all halo reuse is intra-XCD L2.
//
// Schedule (R4's depth-3 counted-vmcnt pipeline, T3+T4):
//   phase g: GATHER(g -> res[g]); s_waitcnt vmcnt(N); s_barrier;
//            STAGE(g+3, g%3)
// STAGE = 3 gll16 per wave (region 96 rows, 1 instr = 4 rows): steady
// queue at the wait = [S(g+1)(3), S(g+2)(3)] -> WAITVM(3) retires exactly
// S(g+1), S(g+2)/S(g+3) stay in flight ACROSS the barrier. Prologue
// WAITVM(6) retires S0; tail 3, 0. Never a full mid-loop drain. Stores:
// res accumulator, bulk store at end -- compiler places actual stores as
// it sees fit (R4-proven).
//
// Staging: __builtin_amdgcn_global_load_lds width=16; one instr per wave =
// 1 KB = 4 rows x 64 floats (wave-uniform LDS base + lane*16; per-lane
// global source). Source chunks are 16B-aligned (x0r multiple of 16
// floats) and never straddle an image row; fully-out-of-image chunks are
// offset-clamped -> finite garbage only in cells no clamped corner of a
// non-fixup pixel references (fixup pixels recomputed from global after;
// same thread stores both -> program order gives the final value).
//
// Kept: flow loads hoisted oldest in the vmcnt queue, fbmask +
// fixup-recompute, mask folded into weights on UNCLIPPED floor coords
// (bit-exact vs reference).

typedef __attribute__((address_space(1))) const void global_cvoid;
typedef __attribute__((address_space(3))) void lds_void;

__device__ __forceinline__ void gll16(const float* g, float* l) {
    __builtin_amdgcn_global_load_lds((global_cvoid*)g, (lds_void*)l, 16, 0, 0);
}

#define WAITVM(n) asm volatile("s_waitcnt vmcnt(" #n ")" ::: "memory")
#define BAR()     __builtin_amdgcn_s_barrier()

// Stage channel plane g into buffer nb: 3 gll16 per wave (quads k*8+wv).
#define STAGE(g, nb) do {                                               \
    const float* pc_ = img + ib + (size_t)(g) * HW;                     \
    _Pragma("unroll")                                                   \
    for (int k_ = 0; k_ < 3; ++k_) {                                    \
        gll16(pc_ + goff[k_], &buf[nb][(k_ * 8 + wv) * 4][0]);          \
    }                                                                   \
} while (0)

// Gather channel g from buffer cb into the register accumulator.
#define GATHER(g, cb) do {                                              \
    const float* pl_ = &buf[cb][0][0];                                  \
    _Pragma("unroll")                                                   \
    for (int p_ = 0; p_ < NPX; ++p_) {                                  \
        const int l_   = lidx[p_];                                      \
        const int dx_  = dxv[p_];                                       \
        const int dyo_ = dyov[p_];                                      \
        const float v00 = pl_[l_];                                      \
        const float v01 = pl_[l_ + dx_];                                \
        const float v10 = pl_[l_ + dyo_];                               \
        const float v11 = pl_[l_ + dx_ + dyo_];                         \
        res[g][p_] = w00[p_]*v00 + w01[p_]*v01                          \
                   + w10[p_]*v10 + w11[p_]*v11;                         \
    }                                                                   \
} while (0)

#define PHASE(g) do {                                                   \
    GATHER(g, (g) % 3);                                                 \
    WAITVM(3);                                                          \
    BAR();                                                              \
    STAGE((g) + 3, (g) % 3);                                            \
} while (0)

__global__ __launch_bounds__(NTHR, 4) void warp_big(
    const float* __restrict__ img,
    const float* __restrict__ flo,
    float* __restrict__ out)
{
    __shared__ float buf[3][REGH][REGW];   // 72 KB -> 2 blocks/CU

    const int t   = threadIdx.x;
    const int bid = blockIdx.x;           // 0..1023
    const int tile = (bid & 7) * 128 + (bid >> 3);   // XCD = one batch
    const int b    = tile >> 7;           // 128 tiles per batch
    const int ti   = tile & 127;
    const int ty   = ti >> 4;             // 0..7
    const int tx   = ti & 15;             // 0..15
    const int xb   = tx * TILW;
    const int yb   = ty * TILH;
    const int x0r  = xb - RPAD;           // region origin (may be negative)
    const int y0r  = yb - RPAD;

    // ---- staging geometry (channel-invariant) ----
    const int lane = t & 63;
    const int wv   = t >> 6;              // wave id 0..7 (wave-uniform)
    const int sub  = lane >> 4;           // row-within-quad 0..3
    const int xch  = x0r + (lane & 15) * 4;  // this lane's 4-float x chunk
    const size_t ib = (size_t)b * CH * HW;

    int goff[3];                          // per-lane staged global offsets
#pragma unroll
    for (int k = 0; k < 3; ++k) {
        const int q  = k * 8 + wv;        // quad 0..23
        const int ry = q * 4 + sub;       // this lane's region row 0..95
        const int gy = min(max(y0r + ry, 0), HH - 1);
        goff[k] = min(max(gy * WW + xch, 0), HW - 4);
    }

    // ---- flow loads FIRST (oldest in the in-order vmcnt queue) ----
    const float* fbp = flo + (size_t)b * 2 * HW;
    float fxv[NPX], fyv[NPX];
#pragma unroll
    for (int p = 0; p < NPX; ++p) {
        const int pix = p * NTHR + t;
        const int hw  = (yb + (pix >> 5)) * WW + xb + (pix & 31);
        fxv[p] = fbp[hw];                 // coalesced
        fyv[p] = fbp[HW + hw];
    }
    asm volatile("" ::: "memory");        // pin: flow loads precede all gll

    // ---- pre-issue staging for groups 0..2 (all three buffers) ----
    STAGE(0, 0);
    STAGE(1, 1);
    STAGE(2, 2);

    // ---- per-pixel precompute (register-only; hides staging latency) ----
    float w00[NPX], w01[NPX], w10[NPX], w11[NPX];
    int   lidx[NPX], dxv[NPX], dyov[NPX], obase[NPX];
    int   fbmask = 0;

#pragma unroll
    for (int p = 0; p < NPX; ++p) {
        const int pix = p * NTHR + t;     // 0..2047 within tile
        const int row = pix >> 5;         // 0..63
        const int col = pix & 31;
        const int h   = yb + row;
        const int w   = xb + col;
        obase[p] = h * WW + w;

        const float gx = (float)w + fxv[p];
        const float gy = (float)h + fyv[p];

        const float x0f = floorf(gx), y0f = floorf(gy);
        const float wx1 = gx - x0f, wx0 = 1.0f - wx1;
        const float wy1 = gy - y0f, wy0 = 1.0f - wy1;

        const bool vx0 = (x0f >= 0.0f)        && (x0f <= (float)(WW - 1));
        const bool vx1 = (x0f + 1.0f >= 0.0f) && (x0f + 1.0f <= (float)(WW - 1));
        const bool vy0 = (y0f >= 0.0f)        && (y0f <= (float)(HH - 1));
        const bool vy1 = (y0f + 1.0f >= 0.0f) && (y0f + 1.0f <= (float)(HH - 1));

        float a00 = wx0 * wy0 * ((vx0 && vy0) ? 1.0f : 0.0f);
        float a01 = wx1 * wy0 * ((vx1 && vy0) ? 1.0f : 0.0f);
        float a10 = wx0 * wy1 * ((vx0 && vy1) ? 1.0f : 0.0f);
        float a11 = wx1 * wy1 * ((vx1 && vy1) ? 1.0f : 0.0f);

        const float msum = a00 + a01 + a10 + a11;
        const float mask = (msum < 0.9999f) ? 0.0f : 1.0f;
        w00[p] = a00 * mask; w01[p] = a01 * mask;
        w10[p] = a10 * mask; w11[p] = a11 * mask;

        const int x0 = min(max((int)x0f, 0), WW - 1);
        const int x1 = min(max((int)x0f + 1, 0), WW - 1);
        const int y0 = min(max((int)y0f, 0), HH - 1);
        const int y1 = min(max((int)y0f + 1, 0), HH - 1);

        const int dx = x1 - x0;           // 0 or 1
        const int dy = y1 - y0;
        dxv[p]  = dx;
        dyov[p] = dy * REGW;

        const int xl = x0 - x0r;          // region-local (may be out of range)
        const int yl = y0 - y0r;
        if (!((xl >= 0) && (xl + dx <= REGW - 1) &&
              (yl >= 0) && (yl + dy <= REGH - 1)))
            fbmask |= (1 << p);
        // Clamp: no-op for in-region pixels, safe-finite for fixup pixels.
        lidx[p] = min(max(yl, 0), REGH - 2) * REGW + min(max(xl, 0), REGW - 2);
    }

    float res[CH][NPX];                   // register output accumulator

    // ---- prologue handoff: retire S0 only (S1,S2 stay in flight) ----
    WAITVM(6);
    BAR();

    // ---- 16 phases, counted vmcnt, never a full mid-loop drain ----
    PHASE(0);   PHASE(1);   PHASE(2);   PHASE(3);
    PHASE(4);   PHASE(5);   PHASE(6);   PHASE(7);
    PHASE(8);   PHASE(9);   PHASE(10);  PHASE(11);
    PHASE(12);
    // g=13: no STAGE(16); queue=[S14,S15]=6 -> wait(3) retires S14.
    GATHER(13, 1);  WAITVM(3);  BAR();
    // g=14: queue=[S15]=3 -> wait(0) retires S15.
    GATHER(14, 2);  WAITVM(0);  BAR();
    GATHER(15, 0);                        // last group: nothing in flight

    // ---- bulk store: coalesced per channel ----
#pragma unroll
    for (int c = 0; c < CH; ++c) {
        float* o0 = out + ib + (size_t)c * HW;
#pragma unroll
        for (int p = 0; p < NPX; ++p)
            o0[obase[p]] = res[c][p];
    }

    // ---- fixup: redo fallback pixels from global (all 16 channels) ----
    // Rare path (~2% of pixels). Exact reference math; L2/L3-warm loads.
    if (fbmask) {
#pragma unroll
        for (int p = 0; p < NPX; ++p) {
            if (!(fbmask & (1 << p))) continue;
            const int pix = p * NTHR + t;
            const int row = pix >> 5;
            const int col = pix & 31;
            const int h   = yb + row;
            const int w   = xb + col;
            const int hw  = h * WW + w;

            const float gx = (float)w + fxv[p];
            const float gy = (float)h + fyv[p];

            const float x0f = floorf(gx), y0f = floorf(gy);
            const float wx1 = gx - x0f, wx0 = 1.0f - wx1;
            const float wy1 = gy - y0f, wy0 = 1.0f - wy1;

            const bool vx0 = (x0f >= 0.0f)        && (x0f <= (float)(WW - 1));
            const bool vx1 = (x0f + 1.0f >= 0.0f) && (x0f + 1.0f <= (float)(WW - 1));
            const bool vy0 = (y0f >= 0.0f)        && (y0f <= (float)(HH - 1));
            const bool vy1 = (y0f + 1.0f >= 0.0f) && (y0f + 1.0f <= (float)(HH - 1));

            float a00 = wx0 * wy0 * ((vx0 && vy0) ? 1.0f : 0.0f);
            float a01 = wx1 * wy0 * ((vx1 && vy0) ? 1.0f : 0.0f);
            float a10 = wx0 * wy1 * ((vx0 && vy1) ? 1.0f : 0.0f);
            float a11 = wx1 * wy1 * ((vx1 && vy1) ? 1.0f : 0.0f);

            const float msum = a00 + a01 + a10 + a11;
            const float mask = (msum < 0.9999f) ? 0.0f : 1.0f;
            a00 *= mask; a01 *= mask; a10 *= mask; a11 *= mask;

            const int x0 = min(max((int)x0f, 0), WW - 1);
            const int x1 = min(max((int)x0f + 1, 0), WW - 1);
            const int y0 = min(max((int)y0f, 0), HH - 1);
            const int y1 = min(max((int)y0f + 1, 0), HH - 1);

            const int gA  = y0 * WW + x0;
            const int dx  = x1 - x0;
            const int dyo = (y1 - y0) * WW;

            const float* ic = img + ib;
            float*       oc = out + ib + hw;
            for (int c = 0; c < CH; ++c) {
                const float* pc = ic + (size_t)c * HW;
                const float v = a00 * pc[gA]
                              + a01 * pc[gA + dx]
                              + a10 * pc[gA + dyo]
                              + a11 * pc[gA + dx + dyo];
                oc[(size_t)c * HW] = v;
            }
        }
    }
}

extern "C" void kernel_launch(void* const* d_in, const int* in_sizes, int n_in,
                              void* d_out, int out_size, void* d_ws, size_t ws_size,
                              hipStream_t stream) {
    const float* img = (const float*)d_in[0];  // [8,16,512,512] fp32
    const float* flo = (const float*)d_in[1];  // [8,2,512,512] fp32
    float* out = (float*)d_out;                // [8,16,512,512] fp32

    const int blocks = BATCH * (WW / TILW) * (HH / TILH);  // 1024
    warp_big<<<blocks, NTHR, 0, stream>>>(img, flo, out);
}